// Round 9
// baseline (911.688 us; speedup 1.0000x reference)
//
#include <hip/hip_runtime.h>
#include <math.h>

#define NCLS 100
#define NBINS 15
// Swizzled conf cell: c*15 + (c>>2) + b. Class stride 61 (coprime with 32
// banks) -> rotated lanes hit distinct banks. Max idx 99*15+24+14 = 1523.
#define CONF_CELLS 1526
#define ACC_CELLS  (NCLS * NBINS)

__device__ __forceinline__ void fadd(float* p, float v) { unsafeAtomicAdd(p, v); }

// Row-per-thread, two passes. Pass 1: float4 sweep -> exp-sum (sum only).
// Pass 2: rotated per-element walk (lane l starts at class l, wraps mod 100)
// -> all 64 lanes touch distinct classes every step: unconditional ds_add
// with zero same-address collisions and zero bank conflicts.
__global__ __launch_bounds__(256) void ece_main_kernel(
    const float* __restrict__ logits,
    const int* __restrict__ labels,
    float* __restrict__ g_conf,
    float* __restrict__ g_acc,
    int N)
{
    __shared__ float s_conf[CONF_CELLS];
    __shared__ float s_acc[ACC_CELLS];
    for (int i = threadIdx.x; i < CONF_CELLS; i += 256) s_conf[i] = 0.f;
    for (int i = threadIdx.x; i < ACC_CELLS; i += 256) s_acc[i] = 0.f;
    __syncthreads();

    const int row = blockIdx.x * 256 + threadIdx.x;
    const bool valid = (row < N);
    const int rclamp = valid ? row : (N - 1);
    const float* rp = logits + (size_t)rclamp * NCLS;
    const int lab = valid ? labels[rclamp] : -1;   // -1: matches no class

    // Pass 1: exp-sum of the row (keep only the sum; partial unroll caps VGPRs).
    float s0 = 0.f, s1 = 0.f, s2 = 0.f, s3 = 0.f;
    const float4* rp4 = (const float4*)rp;
    #pragma unroll 5
    for (int j = 0; j < NCLS / 4; ++j) {
        float4 x = rp4[j];
        s0 += __expf(x.x);
        s1 += __expf(x.y);
        s2 += __expf(x.z);
        s3 += __expf(x.w);
    }
    const float inv = valid
        ? __builtin_amdgcn_rcpf((s0 + s1) + (s2 + s3)) : 0.f;

    // Pass 2: rotated class walk. c starts at lane id -> 64 distinct classes
    // per step across the wave, forever (lockstep increment mod 100).
    int c = threadIdx.x & 63;
    #pragma unroll 5
    for (int step = 0; step < NCLS; ++step) {
        const float p = __expf(rp[c]) * inv;      // L2/L3 hit (pass-1 warm)
        // reference bin: clip(ceil(p*15)-1, 0, 14); p==0 (pad) clamped to 0
        int b = min(max((int)ceilf(p * 15.f), 1), NBINS);   // b-1 = bin
        fadd(&s_conf[c * NBINS + (c >> 2) + b - 1], p);     // unconditional
        if (c == lab) fadd(&s_acc[c * NBINS + b - 1], 1.f); // 1 lane/row total
        ++c;
        if (c == NCLS) c = 0;
    }

    __syncthreads();
    for (int i = threadIdx.x; i < CONF_CELLS; i += 256) {
        const float v = s_conf[i];
        if (v != 0.f) fadd(&g_conf[i], v);
    }
    for (int i = threadIdx.x; i < ACC_CELLS; i += 256) {
        const float a = s_acc[i];
        if (a != 0.f) fadd(&g_acc[i], a);
    }
}

// Finalize: per-class sum_b |conf - acc| / N (conf swizzled), then mean.
__global__ __launch_bounds__(128) void ece_final_kernel(
    const float* __restrict__ g_conf,
    const float* __restrict__ g_acc,
    float* __restrict__ out,
    float invN)
{
    __shared__ float red[128];
    const int t = threadIdx.x;
    float s = 0.f;
    if (t < NCLS) {
        const int cb = t * NBINS + (t >> 2);
        float sum = 0.f;
        #pragma unroll
        for (int b = 0; b < NBINS; ++b)
            sum += fabsf(g_conf[cb + b] - g_acc[t * NBINS + b]);
        s = sum * invN;
        out[1 + t] = s;
    }
    red[t] = s;
    __syncthreads();
    #pragma unroll
    for (int off = 64; off > 0; off >>= 1) {
        if (t < off) red[t] += red[t + off];
        __syncthreads();
    }
    if (t == 0) out[0] = red[0] * (1.0f / (float)NCLS);
}

extern "C" void kernel_launch(void* const* d_in, const int* in_sizes, int n_in,
                              void* d_out, int out_size, void* d_ws, size_t ws_size,
                              hipStream_t stream)
{
    const float* logits = (const float*)d_in[0];
    const int*   labels = (const int*)d_in[1];
    const int N = in_sizes[1];
    float* out = (float*)d_out;

    float* g_conf = (float*)d_ws;            // [CONF_CELLS] (swizzled)
    float* g_acc  = g_conf + CONF_CELLS;     // [ACC_CELLS]

    (void)hipMemsetAsync(d_ws, 0,
                         (size_t)(CONF_CELLS + ACC_CELLS) * sizeof(float), stream);

    // One row per thread; 1954 blocks all co-resident (256 CU x 8 blocks).
    const int blocks = (N + 255) / 256;
    ece_main_kernel<<<blocks, 256, 0, stream>>>(logits, labels, g_conf, g_acc, N);
    ece_final_kernel<<<1, 128, 0, stream>>>(g_conf, g_acc, out, 1.0f / (float)N);
}

// Round 10
// 846.955 us; speedup vs baseline: 1.0764x; 1.0764x over previous
//
#include <hip/hip_runtime.h>
#include <math.h>

#define NCLS 100
#define NBINS 15
// Swizzled cell: c*15 + (c>>2) + b. Sized for junk classes c in [100,128)
// (inactive lanes add 0.0 there; never flushed as nonzero).
#define CELLS 1952
#define RPI 8

__device__ __forceinline__ void fadd(float* p, float v) { unsafeAtomicAdd(p, v); }

template <int CTRL>
__device__ __forceinline__ float dpp_add(float x) {
    int y = __builtin_amdgcn_update_dpp(0, __builtin_bit_cast(int, x),
                                        CTRL, 0xf, 0xf, true);
    return x + __builtin_bit_cast(float, y);
}
__device__ __forceinline__ float rlf(float x, int l) {
    return __builtin_bit_cast(float,
        __builtin_amdgcn_readlane(__builtin_bit_cast(int, x), l));
}

// Wave-per-row; lane owns classes (2l, 2l+1) -> one dwordx2 per row.
// Lanes always hit DISTINCT (class,bin) cells => conf/acc adds are
// unconditional ds_add_f32 (no branches, no exec churn, no bin-0 trick).
__global__ __launch_bounds__(256) void ece_main_kernel(
    const float* __restrict__ logits,
    const int* __restrict__ labels,
    float* __restrict__ g_conf,
    float* __restrict__ g_acc,
    int N)
{
    __shared__ float s_conf[CELLS];
    __shared__ float s_acc[CELLS];
    for (int i = threadIdx.x; i < CELLS; i += 256) { s_conf[i] = 0.f; s_acc[i] = 0.f; }
    __syncthreads();

    const int lane   = threadIdx.x & 63;
    const int wave   = threadIdx.x >> 6;
    const int gwave  = blockIdx.x * 4 + wave;
    const int nwaves = gridDim.x * 4;

    const int q    = lane * 2;                       // first owned class
    const bool act = (q < NCLS);                     // lanes 0..49
    const int qoff = act ? q : 0;                    // safe load offset
    const int cell0 = q * NBINS + (q >> 2);          // swizzled class bases
    const int cell1 = (q + 1) * NBINS + ((q + 1) >> 2);

    for (int base = gwave * RPI; base < N; base += nwaves * RPI) {
        const int labv = labels[min(base + lane, N - 1)];  // batched labels

        float e0[RPI], e1[RPI], s[RPI];
        #pragma unroll
        for (int r = 0; r < RPI; ++r) {
            const int rowc = min(base + r, N - 1);         // clamped (no OOB)
            const bool v = act && (base + r < N);
            const float2 x = *(const float2*)(logits + (size_t)rowc * NCLS + qoff);
            e0[r] = __expf(v ? x.x : -1000.f);             // exp(-1000) == 0
            e1[r] = __expf(v ? x.y : -1000.f);
            s[r]  = e0[r] + e1[r];
        }

        // 8 interleaved DPP chains (VALU pipe), total lands in lane 63.
        #pragma unroll
        for (int r = 0; r < RPI; ++r) s[r] = dpp_add<0x111>(s[r]); // row_shr:1
        #pragma unroll
        for (int r = 0; r < RPI; ++r) s[r] = dpp_add<0x112>(s[r]); // row_shr:2
        #pragma unroll
        for (int r = 0; r < RPI; ++r) s[r] = dpp_add<0x114>(s[r]); // row_shr:4
        #pragma unroll
        for (int r = 0; r < RPI; ++r) s[r] = dpp_add<0x118>(s[r]); // row_shr:8
        #pragma unroll
        for (int r = 0; r < RPI; ++r) s[r] = dpp_add<0x142>(s[r]); // bcast:15
        #pragma unroll
        for (int r = 0; r < RPI; ++r) s[r] = dpp_add<0x143>(s[r]); // bcast:31

        #pragma unroll
        for (int r = 0; r < RPI; ++r) {
            const float tot = rlf(s[r], 63);
            const float inv = __builtin_amdgcn_rcpf(fmaxf(tot, 1e-30f));
            const int  lab  = __builtin_amdgcn_readlane(labv, r);
            const bool rv   = (base + r < N);              // guards acc only

            const float p0 = e0[r] * inv;                  // 0 for pad/inactive
            int b0 = min(max((int)ceilf(p0 * 15.f) - 1, 0), NBINS - 1);
            fadd(&s_conf[cell0 + b0], p0);                 // unconditional
            fadd(&s_acc [cell0 + b0], (rv && q == lab) ? 1.f : 0.f);

            const float p1 = e1[r] * inv;
            int b1 = min(max((int)ceilf(p1 * 15.f) - 1, 0), NBINS - 1);
            fadd(&s_conf[cell1 + b1], p1);
            fadd(&s_acc [cell1 + b1], (rv && (q + 1) == lab) ? 1.f : 0.f);
        }
    }

    __syncthreads();
    for (int i = threadIdx.x; i < CELLS; i += 256) {
        const float v = s_conf[i]; if (v != 0.f) fadd(&g_conf[i], v);
        const float a = s_acc[i];  if (a != 0.f) fadd(&g_acc[i], a);
    }
}

// Finalize: per-class sum_b |conf-acc| / N over swizzled cells, then mean.
__global__ __launch_bounds__(128) void ece_final_kernel(
    const float* __restrict__ g_conf,
    const float* __restrict__ g_acc,
    float* __restrict__ out,
    float invN)
{
    __shared__ float red[128];
    const int t = threadIdx.x;
    float s = 0.f;
    if (t < NCLS) {
        const int cb = t * NBINS + (t >> 2);
        float sum = 0.f;
        #pragma unroll
        for (int b = 0; b < NBINS; ++b)
            sum += fabsf(g_conf[cb + b] - g_acc[cb + b]);
        s = sum * invN;
        out[1 + t] = s;
    }
    red[t] = s;
    __syncthreads();
    #pragma unroll
    for (int off = 64; off > 0; off >>= 1) {
        if (t < off) red[t] += red[t + off];
        __syncthreads();
    }
    if (t == 0) out[0] = red[0] * (1.0f / (float)NCLS);
}

extern "C" void kernel_launch(void* const* d_in, const int* in_sizes, int n_in,
                              void* d_out, int out_size, void* d_ws, size_t ws_size,
                              hipStream_t stream)
{
    const float* logits = (const float*)d_in[0];
    const int*   labels = (const int*)d_in[1];
    const int N = in_sizes[1];
    float* out = (float*)d_out;

    float* g_conf = (float*)d_ws;          // [CELLS] swizzled
    float* g_acc  = g_conf + CELLS;        // [CELLS] swizzled

    (void)hipMemsetAsync(d_ws, 0, (size_t)2 * CELLS * sizeof(float), stream);

    // 2048 blocks = 8 blocks/CU (15.6 KB LDS each; VGPR target <= 64).
    const int blocks = 2048;
    ece_main_kernel<<<blocks, 256, 0, stream>>>(logits, labels, g_conf, g_acc, N);
    ece_final_kernel<<<1, 128, 0, stream>>>(g_conf, g_acc, out, 1.0f / (float)N);
}